// Round 24
// baseline (54.753 us; speedup 1.0000x reference)
//
#include <hip/hip_runtime.h>

// Multi-Scale Deformable Attention forward, fp32 in/out.
// B=1, Q=19947, heads=8, D=32, L=4, P=4.
// Levels: (100,150),(50,75),(25,38),(13,19); starts 0,15000,18750,19700.
//
// - Head-per-XCD: blockIdx.x%8 == head rides round-robin XCD dispatch;
//   fp16 paired-row slice (2.55 MB/XCD) L2-resident.
// - Paired rows [t][g][slot][8ch]: row t = 128 B holds tokens {t,t+1};
//   one dense line serves both bilinear x-corners (best gather 41.4 us).
// - LDS metadata once per (pair,sample): 16 B entries {cY0,cY1,rb0,rb1}.
// - R24: R23's load-all-then-compute + __builtin_amdgcn_sched_barrier(0)
//   between the load pass and the FMA pass. The scheduler kept fusing
//   loads back into the FMA loop (VGPR stayed 32 across R16/R22/R23);
//   the sched_barrier is an instruction-motion wall -> 16 outstanding
//   vmem/wave must materialize. VGPR is the tell (~32 = failed again,
//   ~120 = materialized).
// - Rejected: R11/R12 dedup-by-comm, R17 pure TLP, R18 redundant-meta,
//   R21 flat rows, R20 read-amplified cvt.

typedef float    f32x2 __attribute__((ext_vector_type(2)));
typedef float    f32x4 __attribute__((ext_vector_type(4)));
typedef float    f32x8 __attribute__((ext_vector_type(8)));
typedef _Float16 f16x8 __attribute__((ext_vector_type(8)));

constexpr int HEADS = 8;
constexpr int DCH   = 32;
constexpr int NSP   = 16;
constexpr int NQ    = 19947;
constexpr int HSTR2 = NQ * 64;         // fp16 elems per head slice (paired rows)

// ---- cvt: fp32 [tok][head][ch] -> fp16 paired rows [h][t][g][slot][8ch] ----
__global__ __launch_bounds__(256)
void cvt_pair_kernel(const float* __restrict__ value, _Float16* __restrict__ ws)
{
    const int h = blockIdx.x & 7;                       // head == XCD id
    const int i = (blockIdx.x >> 3) * 256 + threadIdx.x;
    if (i >= NQ * 4) return;
    const int g = i & 3;
    const int t = i >> 2;
    const float* src = value + (size_t)t * 256 + h * 32 + g * 8;
    const f32x4 a = __builtin_nontemporal_load((const f32x4*)src);
    const f32x4 b = __builtin_nontemporal_load((const f32x4*)(src + 4));
    const f32x8 v = {a.x, a.y, a.z, a.w, b.x, b.y, b.z, b.w};
    const f16x8 o = __builtin_convertvector(v, f16x8);
    _Float16* base = ws + (size_t)h * HSTR2;
    *(f16x8*)(base + (size_t)t * 64 + g * 16) = o;                  // row t slot0
    if (t > 0)
        *(f16x8*)(base + (size_t)(t - 1) * 64 + g * 16 + 8) = o;    // row t-1 slot1
    if (t == NQ - 1) {
        const f16x8 z = {};
        *(f16x8*)(base + (size_t)t * 64 + g * 16 + 8) = z;          // pad slot
    }
}

// ---- main kernel ------------------------------------------------------------
__global__ __launch_bounds__(256)
void msda_meta_kernel(const _Float16* __restrict__ ws,
                      const float* __restrict__ loc,
                      const float* __restrict__ attw,
                      float* __restrict__ out)
{
    constexpr int QPB  = 16;             // pairs per block (256 thr / 16 lanes)
    constexpr int PSTR = 132;            // words per pair (528 B, 16 B aligned)
    __shared__ __align__(16) float s_meta[QPB * PSTR];  // 8.25 KB

    const int h    = blockIdx.x & 7;          // head == XCD id
    const int qblk = blockIdx.x >> 3;
    const int q0   = qblk * QPB;
    const int t    = threadIdx.x;

    // ---- phase 1: one metadata item per thread, two 16 B slot entries ----
    {
        const int pair = t >> 4, sp = t & 15;
        const int q = q0 + pair;
        if (q < NQ) {
            const size_t mb = (size_t)(q * HEADS + h);
            const f32x2 xy = __builtin_nontemporal_load(
                (const f32x2*)(loc + mb * (NSP * 2) + sp * 2));
            const float aw = __builtin_nontemporal_load(attw + mb * NSP + sp);

            const int l = sp >> 2;
            const float fW = (l == 0) ? 150.f : (l == 1) ? 75.f : (l == 2) ? 38.f : 19.f;
            const float fH = (l == 0) ? 100.f : (l == 1) ? 50.f : (l == 2) ? 25.f : 13.f;
            const int   W  = (l == 0) ? 150   : (l == 1) ? 75   : (l == 2) ? 38   : 19;
            const int   H  = (l == 0) ? 100   : (l == 1) ? 50   : (l == 2) ? 25   : 13;
            const int   S  = (l == 0) ? 0     : (l == 1) ? 15000: (l == 2) ? 18750: 19700;

            const float x = xy.x * fW - 0.5f;
            const float y = xy.y * fH - 0.5f;
            const float x0f = floorf(x);
            const float y0f = floorf(y);
            const float wx1 = x - x0f;
            const float wy1 = y - y0f;
            const float wx0 = 1.f - wx1;
            const float wy0 = 1.f - wy1;
            const int x0 = (int)x0f, y0 = (int)y0f;   // in [-1, W-1]
            const int x1 = x0 + 1,   y1 = y0 + 1;     // in [0, W]

            const float wx0m = ((unsigned)x0 < (unsigned)W) ? wx0 : 0.f;
            const float wx1m = ((unsigned)x1 < (unsigned)W) ? wx1 : 0.f;
            const float wy0m = ((unsigned)y0 < (unsigned)H) ? aw * wy0 : 0.f;
            const float wy1m = ((unsigned)y1 < (unsigned)H) ? aw * wy1 : 0.f;
            const float c00 = wy0m * wx0m;
            const float c01 = wy0m * wx1m;
            const float c10 = wy1m * wx0m;
            const float c11 = wy1m * wx1m;

            const int cx0 = max(x0, 0), cx1 = min(x1, W - 1);
            const int cy0 = max(y0, 0), cy1 = min(y1, H - 1);
            const bool xi = cx1 > cx0;     // slot1 really is corner x1
            const int rb0 = S + cy0 * W + cx0;   // paired row index, y0
            const int rb1 = S + cy1 * W + cx0;   // paired row index, y1

            float* m = &s_meta[pair * PSTR + sp * 8];
            f32x4 e0, e1;
            e0.x = xi ? c00 : (c00 + c01);
            e0.y = xi ? c10 : (c10 + c11);
            e0.z = __int_as_float(rb0);
            e0.w = __int_as_float(rb1);
            e1.x = xi ? c01 : 0.f;
            e1.y = xi ? c11 : 0.f;
            e1.z = __int_as_float(rb0);
            e1.w = __int_as_float(rb1);
            *(f32x4*)(m)     = e0;         // slot 0 entry
            *(f32x4*)(m + 4) = e1;         // slot 1 entry
        }
    }
    __syncthreads();

    // ---- phase 2: load ALL 16 rows, sched_barrier, then FMA pass ----
    const int pair = t >> 4;
    const int lane = t & 15;
    const int g    = lane & 3;            // ch group (8 ch)
    const int s    = (lane >> 2) & 1;     // token slot (x corner)
    const int half = lane >> 3;           // sample half: 0 -> sp 0-7, 1 -> 8-15
    const int q    = q0 + pair;
    if (q >= NQ) return;

    const float* mbase = &s_meta[pair * PSTR + (half * 8) * 8 + s * 4];
    const _Float16* vf = ws + (size_t)h * HSTR2 + g * 16 + s * 8;

    // coefficients to registers first (tiny), then issue all 16 loads
    float fA[8], fB[8];
    f16x8 ga[8], gb[8];
#pragma unroll
    for (int u = 0; u < 8; ++u) {
        const f32x4 e = *(const f32x4*)(mbase + u * 8);
        fA[u] = e.x;
        fB[u] = e.y;
        ga[u] = *(const f16x8*)(vf + (size_t)__float_as_int(e.z) * 64);
        gb[u] = *(const f16x8*)(vf + (size_t)__float_as_int(e.w) * 64);
    }

    // instruction-motion wall: loads above may NOT sink past this point
    __builtin_amdgcn_sched_barrier(0);

    f32x8 acc = {0.f, 0.f, 0.f, 0.f, 0.f, 0.f, 0.f, 0.f};
#pragma unroll
    for (int u = 0; u < 8; ++u) {
#pragma unroll
        for (int k = 0; k < 8; ++k) {
            acc[k] += fA[u] * (float)ga[u][k];
            acc[k] += fB[u] * (float)gb[u][k];
        }
    }

    // combine slots (xor 4) then halves (xor 8)
#pragma unroll
    for (int k = 0; k < 8; ++k) acc[k] += __shfl_xor(acc[k], 4);
#pragma unroll
    for (int k = 0; k < 8; ++k) acc[k] += __shfl_xor(acc[k], 8);

    if (s == 0) {   // 8 lanes (half,g) x 16 B = contiguous 128 B per pair
        float* op = out + (size_t)(q * HEADS + h) * DCH + g * 8 + half * 4;
        const f32x4 part = half ? f32x4{acc[4], acc[5], acc[6], acc[7]}
                                : f32x4{acc[0], acc[1], acc[2], acc[3]};
        __builtin_nontemporal_store(part, (f32x4*)op);
    }
}

// ---- fp32 direct fallback (correctness only, tiny ws) ----------------------
__global__ __launch_bounds__(256)
void msda_f32_kernel(const float* __restrict__ value,
                     const float* __restrict__ loc,
                     const float* __restrict__ attw,
                     float* __restrict__ out)
{
    const int t    = blockIdx.x * blockDim.x + threadIdx.x;
    const int pair = t >> 3;
    const int d0   = (t & 7) * 4;
    if (pair >= NQ * HEADS) return;
    const int h = pair & 7;

    const float* locp = loc  + (size_t)pair * (NSP * 2);
    const float* awp  = attw + (size_t)pair * NSP;
    f32x4 acc = {0.f, 0.f, 0.f, 0.f};

#pragma unroll
    for (int sp = 0; sp < NSP; ++sp) {
        const int l = sp >> 2;
        const int W = (l == 0) ? 150 : (l == 1) ? 75 : (l == 2) ? 38 : 19;
        const int H = (l == 0) ? 100 : (l == 1) ? 50 : (l == 2) ? 25 : 13;
        const int S = (l == 0) ? 0 : (l == 1) ? 15000 : (l == 2) ? 18750 : 19700;
        const float x = locp[sp * 2] * W - 0.5f;
        const float y = locp[sp * 2 + 1] * H - 0.5f;
        const float aw = awp[sp];
        const float x0f = floorf(x), y0f = floorf(y);
        const float wx1 = x - x0f, wy1 = y - y0f;
        const float wx0 = 1.f - wx1, wy0 = 1.f - wy1;
        const int x0 = (int)x0f, y0 = (int)y0f, x1 = x0 + 1, y1 = y0 + 1;
        const float wx0m = ((unsigned)x0 < (unsigned)W) ? wx0 : 0.f;
        const float wx1m = ((unsigned)x1 < (unsigned)W) ? wx1 : 0.f;
        const float wy0m = ((unsigned)y0 < (unsigned)H) ? aw * wy0 : 0.f;
        const float wy1m = ((unsigned)y1 < (unsigned)H) ? aw * wy1 : 0.f;
        const int cx0 = max(x0, 0), cx1 = min(x1, W - 1);
        const int cy0 = max(y0, 0), cy1 = min(y1, H - 1);
        const size_t r0 = (size_t)(S + cy0 * W), r1 = (size_t)(S + cy1 * W);
        const f32x4 g00 = *(const f32x4*)(value + ((r0 + cx0) * 8 + h) * DCH + d0);
        const f32x4 g01 = *(const f32x4*)(value + ((r0 + cx1) * 8 + h) * DCH + d0);
        const f32x4 g10 = *(const f32x4*)(value + ((r1 + cx0) * 8 + h) * DCH + d0);
        const f32x4 g11 = *(const f32x4*)(value + ((r1 + cx1) * 8 + h) * DCH + d0);
        acc += g00 * (wy0m * wx0m);
        acc += g01 * (wy0m * wx1m);
        acc += g10 * (wy1m * wx0m);
        acc += g11 * (wy1m * wx1m);
    }
    *(f32x4*)(out + (size_t)pair * DCH + d0) = acc;
}

extern "C" void kernel_launch(void* const* d_in, const int* in_sizes, int n_in,
                              void* d_out, int out_size, void* d_ws, size_t ws_size,
                              hipStream_t stream) {
    const float* value = (const float*)d_in[0];
    const float* loc   = (const float*)d_in[3];
    const float* attw  = (const float*)d_in[4];
    float* out = (float*)d_out;

    const size_t pair_bytes = (size_t)NQ * HEADS * 64 * sizeof(_Float16); // 20.4 MB

    if (ws_size >= pair_bytes) {
        _Float16* ws = (_Float16*)d_ws;
        const int cgrid = ((NQ * 4 + 255) / 256) * HEADS;                 // XCD-aligned
        cvt_pair_kernel<<<cgrid, 256, 0, stream>>>(value, ws);
        const int qblocks = (NQ + 15) / 16;                               // 1247
        msda_meta_kernel<<<qblocks * HEADS, 256, 0, stream>>>(ws, loc, attw, out);
    } else {
        const int total = NQ * HEADS * 8;
        msda_f32_kernel<<<(total + 255) / 256, 256, 0, stream>>>(value, loc, attw, out);
    }
}

// Round 25
// 52.756 us; speedup vs baseline: 1.0378x; 1.0378x over previous
//
#include <hip/hip_runtime.h>

// Multi-Scale Deformable Attention forward, fp32 in/out.
// B=1, Q=19947, heads=8, D=32, L=4, P=4.
// Levels: (100,150),(50,75),(25,38),(13,19); starts 0,15000,18750,19700.
//
// - Head-per-XCD: blockIdx.x%8 == head rides round-robin XCD dispatch;
//   fp16 paired-row slice (2.55 MB/XCD) L2-resident.
// - Paired rows [t][g][slot][8ch]: row t = 128 B holds tokens {t,t+1};
//   one dense line serves both bilinear x-corners. Gather pinned at
//   ~41.4 us (R22): request-halving helped (47->41.5), extra TLP (R17),
//   MLP (R16/R22/R23/R24 sched_barrier) all flat -> L2-path wall.
// - R25: LDS-staged cvt. Stage 65 tokens/block (coalesced 32 B reads),
//   then write 64 paired rows as contiguous 16 B chunks (threads 0-7 =
//   row0's 128 B) -> coalesced stores. R19-R24 cvt did 2 scattered 16 B
//   stores/thread at 128 B stride = ~12 us; floor is ~4 us.
// - Phase 2 = R22's interleaved form (best measured; VGPR 32, occ 65%).

typedef float    f32x2 __attribute__((ext_vector_type(2)));
typedef float    f32x4 __attribute__((ext_vector_type(4)));
typedef float    f32x8 __attribute__((ext_vector_type(8)));
typedef _Float16 f16x8 __attribute__((ext_vector_type(8)));

constexpr int HEADS = 8;
constexpr int DCH   = 32;
constexpr int NSP   = 16;
constexpr int NQ    = 19947;
constexpr int HSTR2 = NQ * 64;         // fp16 elems per head slice (paired rows)

// ---- cvt: LDS-staged, coalesced in and out ---------------------------------
// out layout: row t (128 B) = [g][slot][8ch], slot s = token t+s.
__global__ __launch_bounds__(256)
void cvt_stage_kernel(const float* __restrict__ value, _Float16* __restrict__ ws)
{
    __shared__ _Float16 s_tok[65 * 32 + 16];   // 65 tokens x 32 ch fp16

    const int h  = blockIdx.x & 7;             // head == XCD id
    const int r0 = (blockIdx.x >> 3) * 64;     // first row of this block
    const int t  = threadIdx.x;

    // stage tokens r0 .. r0+64 (260 chunks of 8 ch, coalesced 32 B reads)
    for (int c = t; c < 260; c += 256) {
        const int tt = c >> 2, g = c & 3;
        const int tok = r0 + tt;
        f16x8 o = {};
        if (tok < NQ) {
            const float* src = value + (size_t)tok * 256 + h * 32 + g * 8;
            const f32x4 a = __builtin_nontemporal_load((const f32x4*)src);
            const f32x4 b = __builtin_nontemporal_load((const f32x4*)(src + 4));
            const f32x8 v = {a.x, a.y, a.z, a.w, b.x, b.y, b.z, b.w};
            o = __builtin_convertvector(v, f16x8);
        }
        *(f16x8*)(s_tok + tt * 32 + g * 8) = o;
    }
    __syncthreads();

    // write 64 paired rows: thread (rr,j) emits row rr's j-th 16 B chunk
    // chunk j -> g = j>>1, s = j&1, elem offset j*8 -> fully contiguous
#pragma unroll
    for (int it = 0; it < 2; ++it) {
        const int w  = t + it * 256;           // 0..511
        const int rr = w >> 3;
        const int j  = w & 7;
        const int g  = j >> 1, s = j & 1;
        const int row = r0 + rr;
        if (row < NQ) {
            const f16x8 v = *(const f16x8*)(s_tok + (rr + s) * 32 + g * 8);
            __builtin_nontemporal_store(v,
                (f16x8*)(ws + (size_t)h * HSTR2 + (size_t)row * 64 + j * 8));
        }
    }
}

// ---- main kernel (R22 form, proven 41.4 us) --------------------------------
__global__ __launch_bounds__(256)
void msda_meta_kernel(const _Float16* __restrict__ ws,
                      const float* __restrict__ loc,
                      const float* __restrict__ attw,
                      float* __restrict__ out)
{
    constexpr int QPB  = 16;             // pairs per block (256 thr / 16 lanes)
    constexpr int PSTR = 132;            // words per pair (528 B, 16 B aligned)
    __shared__ __align__(16) float s_meta[QPB * PSTR];  // 8.25 KB

    const int h    = blockIdx.x & 7;          // head == XCD id
    const int qblk = blockIdx.x >> 3;
    const int q0   = qblk * QPB;
    const int t    = threadIdx.x;

    // ---- phase 1: one metadata item per thread, two 16 B slot entries ----
    {
        const int pair = t >> 4, sp = t & 15;
        const int q = q0 + pair;
        if (q < NQ) {
            const size_t mb = (size_t)(q * HEADS + h);
            const f32x2 xy = __builtin_nontemporal_load(
                (const f32x2*)(loc + mb * (NSP * 2) + sp * 2));
            const float aw = __builtin_nontemporal_load(attw + mb * NSP + sp);

            const int l = sp >> 2;
            const float fW = (l == 0) ? 150.f : (l == 1) ? 75.f : (l == 2) ? 38.f : 19.f;
            const float fH = (l == 0) ? 100.f : (l == 1) ? 50.f : (l == 2) ? 25.f : 13.f;
            const int   W  = (l == 0) ? 150   : (l == 1) ? 75   : (l == 2) ? 38   : 19;
            const int   H  = (l == 0) ? 100   : (l == 1) ? 50   : (l == 2) ? 25   : 13;
            const int   S  = (l == 0) ? 0     : (l == 1) ? 15000: (l == 2) ? 18750: 19700;

            const float x = xy.x * fW - 0.5f;
            const float y = xy.y * fH - 0.5f;
            const float x0f = floorf(x);
            const float y0f = floorf(y);
            const float wx1 = x - x0f;
            const float wy1 = y - y0f;
            const float wx0 = 1.f - wx1;
            const float wy0 = 1.f - wy1;
            const int x0 = (int)x0f, y0 = (int)y0f;   // in [-1, W-1]
            const int x1 = x0 + 1,   y1 = y0 + 1;     // in [0, W]

            const float wx0m = ((unsigned)x0 < (unsigned)W) ? wx0 : 0.f;
            const float wx1m = ((unsigned)x1 < (unsigned)W) ? wx1 : 0.f;
            const float wy0m = ((unsigned)y0 < (unsigned)H) ? aw * wy0 : 0.f;
            const float wy1m = ((unsigned)y1 < (unsigned)H) ? aw * wy1 : 0.f;
            const float c00 = wy0m * wx0m;
            const float c01 = wy0m * wx1m;
            const float c10 = wy1m * wx0m;
            const float c11 = wy1m * wx1m;

            const int cx0 = max(x0, 0), cx1 = min(x1, W - 1);
            const int cy0 = max(y0, 0), cy1 = min(y1, H - 1);
            const bool xi = cx1 > cx0;     // slot1 really is corner x1
            const int rb0 = S + cy0 * W + cx0;   // paired row index, y0
            const int rb1 = S + cy1 * W + cx0;   // paired row index, y1

            float* m = &s_meta[pair * PSTR + sp * 8];
            f32x4 e0, e1;
            e0.x = xi ? c00 : (c00 + c01);
            e0.y = xi ? c10 : (c10 + c11);
            e0.z = __int_as_float(rb0);
            e0.w = __int_as_float(rb1);
            e1.x = xi ? c01 : 0.f;
            e1.y = xi ? c11 : 0.f;
            e1.z = __int_as_float(rb0);
            e1.w = __int_as_float(rb1);
            *(f32x4*)(m)     = e0;         // slot 0 entry
            *(f32x4*)(m + 4) = e1;         // slot 1 entry
        }
    }
    __syncthreads();

    // ---- phase 2: gather + accumulate (R22 interleaved form) ----
    const int pair = t >> 4;
    const int lane = t & 15;
    const int g    = lane & 3;            // ch group (8 ch)
    const int s    = (lane >> 2) & 1;     // token slot (x corner)
    const int half = lane >> 3;           // sample half: 0 -> sp 0-7, 1 -> 8-15
    const int q    = q0 + pair;
    if (q >= NQ) return;

    const float* mbase = &s_meta[pair * PSTR + (half * 8) * 8 + s * 4];
    f32x4 e0 = *(const f32x4*)(mbase + 0 * 8);
    f32x4 e1 = *(const f32x4*)(mbase + 1 * 8);
    f32x4 e2 = *(const f32x4*)(mbase + 2 * 8);
    f32x4 e3 = *(const f32x4*)(mbase + 3 * 8);
    f32x4 e4 = *(const f32x4*)(mbase + 4 * 8);
    f32x4 e5 = *(const f32x4*)(mbase + 5 * 8);
    f32x4 e6 = *(const f32x4*)(mbase + 6 * 8);
    f32x4 e7 = *(const f32x4*)(mbase + 7 * 8);

    const _Float16* vf = ws + (size_t)h * HSTR2 + g * 16 + s * 8;

    f32x8 acc = {0.f, 0.f, 0.f, 0.f, 0.f, 0.f, 0.f, 0.f};

#define SAMPLE(E)                                                         \
    {                                                                     \
        const int rb0 = __float_as_int(E.z);                              \
        const int rb1 = __float_as_int(E.w);                              \
        const f16x8 ga = *(const f16x8*)(vf + (size_t)rb0 * 64);          \
        const f16x8 gb = *(const f16x8*)(vf + (size_t)rb1 * 64);          \
        _Pragma("unroll")                                                 \
        for (int k = 0; k < 8; ++k) {                                     \
            acc[k] += E.x * (float)ga[k];                                 \
            acc[k] += E.y * (float)gb[k];                                 \
        }                                                                 \
    }
    SAMPLE(e0) SAMPLE(e1) SAMPLE(e2) SAMPLE(e3)
    SAMPLE(e4) SAMPLE(e5) SAMPLE(e6) SAMPLE(e7)
#undef SAMPLE

    // combine slots (xor 4) then halves (xor 8)
#pragma unroll
    for (int k = 0; k < 8; ++k) acc[k] += __shfl_xor(acc[k], 4);
#pragma unroll
    for (int k = 0; k < 8; ++k) acc[k] += __shfl_xor(acc[k], 8);

    if (s == 0) {   // 8 lanes (half,g) x 16 B = contiguous 128 B per pair
        float* op = out + (size_t)(q * HEADS + h) * DCH + g * 8 + half * 4;
        const f32x4 part = half ? f32x4{acc[4], acc[5], acc[6], acc[7]}
                                : f32x4{acc[0], acc[1], acc[2], acc[3]};
        __builtin_nontemporal_store(part, (f32x4*)op);
    }
}

// ---- fp32 direct fallback (correctness only, tiny ws) ----------------------
__global__ __launch_bounds__(256)
void msda_f32_kernel(const float* __restrict__ value,
                     const float* __restrict__ loc,
                     const float* __restrict__ attw,
                     float* __restrict__ out)
{
    const int t    = blockIdx.x * blockDim.x + threadIdx.x;
    const int pair = t >> 3;
    const int d0   = (t & 7) * 4;
    if (pair >= NQ * HEADS) return;
    const int h = pair & 7;

    const float* locp = loc  + (size_t)pair * (NSP * 2);
    const float* awp  = attw + (size_t)pair * NSP;
    f32x4 acc = {0.f, 0.f, 0.f, 0.f};

#pragma unroll
    for (int sp = 0; sp < NSP; ++sp) {
        const int l = sp >> 2;
        const int W = (l == 0) ? 150 : (l == 1) ? 75 : (l == 2) ? 38 : 19;
        const int H = (l == 0) ? 100 : (l == 1) ? 50 : (l == 2) ? 25 : 13;
        const int S = (l == 0) ? 0 : (l == 1) ? 15000 : (l == 2) ? 18750 : 19700;
        const float x = locp[sp * 2] * W - 0.5f;
        const float y = locp[sp * 2 + 1] * H - 0.5f;
        const float aw = awp[sp];
        const float x0f = floorf(x), y0f = floorf(y);
        const float wx1 = x - x0f, wy1 = y - y0f;
        const float wx0 = 1.f - wx1, wy0 = 1.f - wy1;
        const int x0 = (int)x0f, y0 = (int)y0f, x1 = x0 + 1, y1 = y0 + 1;
        const float wx0m = ((unsigned)x0 < (unsigned)W) ? wx0 : 0.f;
        const float wx1m = ((unsigned)x1 < (unsigned)W) ? wx1 : 0.f;
        const float wy0m = ((unsigned)y0 < (unsigned)H) ? aw * wy0 : 0.f;
        const float wy1m = ((unsigned)y1 < (unsigned)H) ? aw * wy1 : 0.f;
        const int cx0 = max(x0, 0), cx1 = min(x1, W - 1);
        const int cy0 = max(y0, 0), cy1 = min(y1, H - 1);
        const size_t r0 = (size_t)(S + cy0 * W), r1 = (size_t)(S + cy1 * W);
        const f32x4 g00 = *(const f32x4*)(value + ((r0 + cx0) * 8 + h) * DCH + d0);
        const f32x4 g01 = *(const f32x4*)(value + ((r0 + cx1) * 8 + h) * DCH + d0);
        const f32x4 g10 = *(const f32x4*)(value + ((r1 + cx0) * 8 + h) * DCH + d0);
        const f32x4 g11 = *(const f32x4*)(value + ((r1 + cx1) * 8 + h) * DCH + d0);
        acc += g00 * (wy0m * wx0m);
        acc += g01 * (wy0m * wx1m);
        acc += g10 * (wy1m * wx0m);
        acc += g11 * (wy1m * wx1m);
    }
    *(f32x4*)(out + (size_t)pair * DCH + d0) = acc;
}

extern "C" void kernel_launch(void* const* d_in, const int* in_sizes, int n_in,
                              void* d_out, int out_size, void* d_ws, size_t ws_size,
                              hipStream_t stream) {
    const float* value = (const float*)d_in[0];
    const float* loc   = (const float*)d_in[3];
    const float* attw  = (const float*)d_in[4];
    float* out = (float*)d_out;

    const size_t pair_bytes = (size_t)NQ * HEADS * 64 * sizeof(_Float16); // 20.4 MB

    if (ws_size >= pair_bytes) {
        _Float16* ws = (_Float16*)d_ws;
        const int rblocks = (NQ + 63) / 64;                               // 312
        cvt_stage_kernel<<<rblocks * HEADS, 256, 0, stream>>>(value, ws);
        const int qblocks = (NQ + 15) / 16;                               // 1247
        msda_meta_kernel<<<qblocks * HEADS, 256, 0, stream>>>(ws, loc, attw, out);
    } else {
        const int total = NQ * HEADS * 8;
        msda_f32_kernel<<<(total + 255) / 256, 256, 0, stream>>>(value, loc, attw, out);
    }
}